// Round 4
// baseline (128.668 us; speedup 1.0000x reference)
//
#include <hip/hip_runtime.h>
#include <hip/hip_bf16.h>

// B=64, T=256, D=128, H=8, E=128, H*E=1024.
// Algebra (verified R1-R3): with xw[b]=Ws^T x[b], Sw=sum(Ws):
//   Kw[b,he]   = xw[b] @ Wk[:,he] + Sw*bk[he]
//   wqk[b,h,d] = scale * sum_e Wq[d,h*128+e]*Kw[b,h,e]   (bq, bs drop: shift-invariant)
//   beta[b,h,t]= softmax_t( x[b,t] . wqk[b,h] )
//   xb[b,h,d]  = sum_t beta[b,h,t]*x[b,t,d]
//   res[b,he]  = xb[b,h] @ Wv[:,he] + bv[he]             (sum_t beta = 1)
//   out[b,d']  = res[b] @ Wo[:,d'] + bo[d']
//
// R4: ONE kernel, grid (64,4) x 512. Block (b,p) owns heads {2p,2p+1} and the
// res chunk he in [256p,256p+256) (depends only on its own xb). Final out
// reduction over p via d_ws partials + flag handshake (p==3 consumes).
// Phases C/D rewritten as wave-row GEMV (coalesced float2 rows + shfl_xor
// reduce) — the R3 versions had 4KB-stride lanes (64 lines/instr, ~3.4us each).

#define SCALE 0.08838834764831845f  // 1/sqrt(128)
#define MAGIC 0x13579BDFu

__global__ __launch_bounds__(512)
void ta_one(const float* __restrict__ x,  const float* __restrict__ Wq,
            const float* __restrict__ Wk, const float* __restrict__ bk,
            const float* __restrict__ Wv, const float* __restrict__ bv,
            const float* __restrict__ Wsv,
            const float* __restrict__ Wo, const float* __restrict__ bov,
            float* __restrict__ ws, float* __restrict__ out)
{
    __shared__ float red[4][256];      // scratch partials
    __shared__ float xwS[128];
    __shared__ float kwS[256];         // [hi][e]
    __shared__ float wqkS[256];        // [hi][d], pre-scaled
    __shared__ float betaS[2][256];    // scores then beta
    __shared__ float xbS[256];         // [hi][d]
    __shared__ float resS[256];
    __shared__ float smx[2][4], sms[2][4];
    __shared__ float swS;

    const int tid = threadIdx.x;
    const int b = blockIdx.x, p = blockIdx.y;
    const int w = tid >> 6, l = tid & 63;
    const float* xp0 = x + (size_t)b * 32768;

    // ---- A: xw[d] = sum_t Ws[t]*x[b,t,d]; Sw. (coalesced: lanes = d)
    {
        const int d = tid & 127, tc = tid >> 7;
        float acc = 0.f;
        const float* xp = xp0 + (size_t)(tc * 64) * 128 + d;
        #pragma unroll 16
        for (int j = 0; j < 64; ++j)
            acc += Wsv[tc * 64 + j] * xp[(size_t)j * 128];   // Ws uniform -> s_load
        red[tc][d] = acc;
        if (tid >= 128 && tid < 192) {                       // one wave: Sw
            float v = Wsv[l] + Wsv[l + 64] + Wsv[l + 128] + Wsv[l + 192];
            #pragma unroll
            for (int off = 32; off; off >>= 1) v += __shfl_xor(v, off, 64);
            if (l == 0) swS = v;
        }
        __syncthreads();
        if (tid < 128) xwS[tid] = red[0][tid] + red[1][tid] + red[2][tid] + red[3][tid];
        __syncthreads();
    }

    // ---- B: Kw[e2] = xw . Wk[:, 256p+e2] + Sw*bk. (coalesced: lanes = he)
    {
        const int e2 = tid & 255, kh = tid >> 8;
        const float* wp = Wk + (size_t)(kh * 64) * 1024 + 256 * p + e2;
        float acc = 0.f;
        #pragma unroll 16
        for (int j = 0; j < 64; ++j)
            acc += xwS[kh * 64 + j] * wp[(size_t)j * 1024];  // xwS bcast
        red[kh][e2] = acc;
        __syncthreads();
        if (tid < 256) kwS[tid] = red[0][tid] + red[1][tid] + swS * bk[256 * p + tid];
        __syncthreads();
    }

    // ---- C: wqk[o] = Wq[d, h*128..] . kw[hi]  (wave-row GEMV, coalesced)
    {
        #pragma unroll 4
        for (int i = 0; i < 32; ++i) {
            const int o = w * 32 + i;                 // 0..255
            const int hi = o >> 7, d = o & 127;
            const float2 wv = *(const float2*)(Wq + (size_t)d * 1024 + (2 * p + hi) * 128 + 2 * l);
            const float2 kv = *(const float2*)(kwS + hi * 128 + 2 * l);
            float r = wv.x * kv.x + wv.y * kv.y;
            #pragma unroll
            for (int off = 32; off; off >>= 1) r += __shfl_xor(r, off, 64);
            if (l == 0) wqkS[o] = r * SCALE;
        }
        __syncthreads();
    }

    // ---- D: score[hi][t] = x[t] . wqk[hi]  (wave-row GEMV, coalesced)
    {
        #pragma unroll 4
        for (int i = 0; i < 64; ++i) {
            const int s = w * 64 + i;                 // 0..511
            const int t = s & 255, hi = s >> 8;
            const float2 xv = *(const float2*)(xp0 + (size_t)t * 128 + 2 * l);
            const float2 qv = *(const float2*)(wqkS + hi * 128 + 2 * l);
            float r = xv.x * qv.x + xv.y * qv.y;
            #pragma unroll
            for (int off = 32; off; off >>= 1) r += __shfl_xor(r, off, 64);
            if (l == 0) betaS[hi][t] = r;
        }
        __syncthreads();
    }

    // ---- softmax over t per head (thread = (hi, t))
    {
        const int t = tid & 255, hi = tid >> 8;
        const float v = betaS[hi][t];
        float m = v;
        #pragma unroll
        for (int off = 32; off; off >>= 1) m = fmaxf(m, __shfl_xor(m, off, 64));
        if (l == 0) smx[hi][w & 3] = m;
        __syncthreads();
        const float M = fmaxf(fmaxf(smx[hi][0], smx[hi][1]), fmaxf(smx[hi][2], smx[hi][3]));
        const float e = __expf(v - M);
        float ssum = e;
        #pragma unroll
        for (int off = 32; off; off >>= 1) ssum += __shfl_xor(ssum, off, 64);
        if (l == 0) sms[hi][w & 3] = ssum;
        __syncthreads();
        const float S = sms[hi][0] + sms[hi][1] + sms[hi][2] + sms[hi][3];
        betaS[hi][t] = e / S;
        __syncthreads();
    }

    // ---- E: xb[hi][d] = sum_t beta[hi][t]*x[t][d]  (coalesced: lanes = d)
    {
        const int d = tid & 127, tq = tid >> 7;
        const float* xp = xp0 + (size_t)(tq * 64) * 128 + d;
        const float* b0 = betaS[0] + tq * 64;        // LDS bcast
        const float* b1 = betaS[1] + tq * 64;
        float a0 = 0.f, a1 = 0.f;
        #pragma unroll 8
        for (int j = 0; j < 64; ++j) {
            const float xv = xp[(size_t)j * 128];
            a0 += b0[j] * xv; a1 += b1[j] * xv;
        }
        red[tq][d] = a0; red[tq][128 + d] = a1;
        __syncthreads();
        if (tid < 256) xbS[tid] = red[0][tid] + red[1][tid] + red[2][tid] + red[3][tid];
        __syncthreads();
    }

    // ---- F: res[he2] = xb[hi] . Wv[:, 256p+he2] + bv  (coalesced: lanes = he)
    {
        const int he2 = tid & 255, kh = tid >> 8;
        const int hi = he2 >> 7;
        const float* wp = Wv + (size_t)(kh * 64) * 1024 + 256 * p + he2;
        const float* xbp = xbS + hi * 128 + kh * 64; // bcast
        float acc = 0.f;
        #pragma unroll 16
        for (int j = 0; j < 64; ++j)
            acc += xbp[j] * wp[(size_t)j * 1024];
        red[kh][he2] = acc;
        __syncthreads();
        if (tid < 256) resS[tid] = red[0][tid] + red[1][tid] + bv[256 * p + tid];
        __syncthreads();
    }

    // ---- G: out partial over this he-chunk  (coalesced: lanes = d)
    {
        const int d = tid & 127, rh = tid >> 7;
        const float* wp = Wo + (size_t)(256 * p + rh * 64) * 128 + d;
        const float* rp = resS + rh * 64;            // bcast
        float acc = 0.f;
        #pragma unroll 16
        for (int j = 0; j < 64; ++j)
            acc += rp[j] * wp[(size_t)j * 128];
        red[rh][d] = acc;
        __syncthreads();
    }

    // ---- cross-block reduce over p via d_ws (poisoned 0xAA != MAGIC each call)
    float* part = ws;                               // [64*4*128]
    unsigned* flags = (unsigned*)(ws + 32768);      // [256]
    if (p < 3) {
        if (tid < 128) {
            part[(size_t)(b * 4 + p) * 128 + tid] =
                red[0][tid] + red[1][tid] + red[2][tid] + red[3][tid];
            __threadfence();                        // release own stores
        }
        __syncthreads();
        if (tid == 0) atomicExch(&flags[b * 4 + p], MAGIC);
    } else {
        if (tid == 0) {
            while (atomicCAS(&flags[b * 4 + 0], MAGIC, MAGIC) != MAGIC) {}
            while (atomicCAS(&flags[b * 4 + 1], MAGIC, MAGIC) != MAGIC) {}
            while (atomicCAS(&flags[b * 4 + 2], MAGIC, MAGIC) != MAGIC) {}
        }
        __syncthreads();
        if (tid < 128) {
            float v = bov[tid] + red[0][tid] + red[1][tid] + red[2][tid] + red[3][tid];
            v += atomicAdd(&part[(size_t)(b * 4 + 0) * 128 + tid], 0.f);  // atomic load
            v += atomicAdd(&part[(size_t)(b * 4 + 1) * 128 + tid], 0.f);
            v += atomicAdd(&part[(size_t)(b * 4 + 2) * 128 + tid], 0.f);
            out[(size_t)b * 128 + tid] = v;
        }
    }
}

extern "C" void kernel_launch(void* const* d_in, const int* in_sizes, int n_in,
                              void* d_out, int out_size, void* d_ws, size_t ws_size,
                              hipStream_t stream) {
    const float* x  = (const float*)d_in[0];
    const float* Wq = (const float*)d_in[1];
    // d_in[2] = bq  — softmax shift-invariant, unused
    const float* Wk = (const float*)d_in[3];
    const float* bk = (const float*)d_in[4];
    const float* Wv = (const float*)d_in[5];
    const float* bv = (const float*)d_in[6];
    const float* Ws = (const float*)d_in[7];
    // d_in[8] = bs  — softmax shift-invariant, unused
    const float* Wo = (const float*)d_in[9];
    const float* bo = (const float*)d_in[10];
    float* out = (float*)d_out;
    float* ws  = (float*)d_ws;

    ta_one<<<dim3(64, 4), dim3(512), 0, stream>>>(x, Wq, Wk, bk, Wv, bv, Ws, Wo, bo, ws, out);
}

// Round 5
// 99.336 us; speedup vs baseline: 1.2953x; 1.2953x over previous
//
#include <hip/hip_runtime.h>
#include <hip/hip_bf16.h>

// B=64, T=256, D=128, H=8, E=128, H*E=1024.
// Algebra (verified R1-R4): with xw[b]=Ws^T x[b], Sw=sum(Ws):
//   Kw[b,he]   = xw[b] @ Wk[:,he] + Sw*bk[he]
//   wqk[b,h,d] = scale * sum_e Wq[d,h*128+e]*Kw[b,h,e]   (bq, bs drop: shift-invariant)
//   beta[b,h,t]= softmax_t( x[b,t] . wqk[b,h] )
//   xb[b,h,d]  = sum_t beta[b,h,t]*x[b,t,d]
//   res[b,he]  = xb[b,h] @ Wv[:,he] + bv[he]             (sum_t beta = 1)
//   out[b,d']  = res[b] @ Wo[:,d'] + bo[d']
//
// R5: one kernel, grid (64,4) x 512 (block = (b, head-pair p)). All GEMVs are
// either float4-coalesced column streams (A,B,E,F,G — lane owns 4 outputs) or
// LDS-transpose tiles (C,D — stage [256x32] tile, one thread per output,
// stride-1 b128 LDS dots). NO shfl-reduce chains (R4's 58us came from 6-deep
// ds_bpermute chains in C/D). Cross-block p-reduction: d_ws flag handshake.

#define SCALE 0.08838834764831845f  // 1/sqrt(128)
#define MAGIC 0x13579BDFu

__global__ __launch_bounds__(512)
void ta_one(const float* __restrict__ x,  const float* __restrict__ Wq,
            const float* __restrict__ Wk, const float* __restrict__ bk,
            const float* __restrict__ Wv, const float* __restrict__ bv,
            const float* __restrict__ Wsv,
            const float* __restrict__ Wo, const float* __restrict__ bov,
            float* __restrict__ ws, float* __restrict__ out)
{
    __shared__ __align__(16) float Tf[9216];      // tile / partial exchange
    __shared__ __align__(16) float red[2][256];
    __shared__ __align__(16) float wsS[256];
    __shared__ __align__(16) float xwS[128];
    __shared__ __align__(16) float kwS[256];      // [hi][e]
    __shared__ __align__(16) float wqkS[256];     // [hi][d], pre-scaled
    __shared__ __align__(16) float betaS[2][256]; // scores then beta
    __shared__ __align__(16) float xbS[256];      // [hi][d]
    __shared__ __align__(16) float resS[256];
    __shared__ float smx[2][4], sms[2][4];
    __shared__ float swS;

    const int tid = threadIdx.x;
    const int b = blockIdx.x, p = blockIdx.y;
    const int w = tid >> 6, l = tid & 63;
    const float* xp0 = x + (size_t)b * 32768;

    // ---- stage Ws
    if (tid < 256) wsS[tid] = Wsv[tid];
    __syncthreads();

    // ---- A: xw[d] = sum_t Ws[t]*x[t,d].  lane owns 4 d's; 16 t-chunks.
    {
        const int q = tid & 31, tc = tid >> 5;      // tc in [0,16)
        float4 acc = {0.f, 0.f, 0.f, 0.f};
        const float4* xp = (const float4*)(xp0 + (size_t)(tc * 16) * 128 + 4 * q);
        #pragma unroll
        for (int j = 0; j < 16; ++j) {
            const float4 xv = xp[(size_t)j * 32];
            const float wsv = wsS[tc * 16 + j];
            acc.x += wsv * xv.x; acc.y += wsv * xv.y;
            acc.z += wsv * xv.z; acc.w += wsv * xv.w;
        }
        *(float4*)(Tf + tc * 128 + 4 * q) = acc;
        __syncthreads();
        if (tid < 128) {
            float v = 0.f;
            #pragma unroll
            for (int g = 0; g < 16; ++g) v += Tf[g * 128 + tid];
            xwS[tid] = v;
        } else if (tid < 192) {                     // Sw (once)
            float v = wsS[l] + wsS[l + 64] + wsS[l + 128] + wsS[l + 192];
            #pragma unroll
            for (int off = 32; off; off >>= 1) v += __shfl_xor(v, off, 64);
            if (l == 0) swS = v;
        }
        __syncthreads();
    }

    // ---- B: Kw[e2] = xw . Wk[:,256p+e2] + Sw*bk.  lane owns 4 e2's.
    {
        const int q = tid & 63, kh = tid >> 6;      // kh in [0,8)
        float4 acc = {0.f, 0.f, 0.f, 0.f};
        const float4* wp = (const float4*)(Wk + (size_t)(kh * 16) * 1024 + 256 * p + 4 * q);
        #pragma unroll
        for (int j = 0; j < 16; ++j) {
            const float4 wv = wp[(size_t)j * 256];
            const float xv = xwS[kh * 16 + j];
            acc.x += xv * wv.x; acc.y += xv * wv.y;
            acc.z += xv * wv.z; acc.w += xv * wv.w;
        }
        *(float4*)(Tf + kh * 256 + 4 * q) = acc;
        __syncthreads();
        if (tid < 256) {
            float v = swS * bk[256 * p + tid];
            #pragma unroll
            for (int g = 0; g < 8; ++g) v += Tf[g * 256 + tid];
            kwS[tid] = v;
        }
        __syncthreads();
    }

    // ---- C: wqk[o] = sum_e Wq[d, (2p+hi)*128+e]*kw[hi][e].  LDS-transpose tiles.
    {
        const int o = tid & 255, eh = tid >> 8;     // eh: e-half
        float acc = 0.f;
        for (int tau = 0; tau < 4; ++tau) {
            __syncthreads();                         // protect Tf from prior readers
            #pragma unroll
            for (int r = 0; r < 4; ++r) {
                const int f4 = tid + 512 * r;        // 2048 float4s
                const int oo = f4 >> 3, j4 = f4 & 7;
                const float4 v = *(const float4*)(Wq + (size_t)(oo & 127) * 1024
                                    + (2 * p + (oo >> 7)) * 128 + tau * 32 + 4 * j4);
                *(float4*)(Tf + oo * 36 + 4 * j4) = v;
            }
            __syncthreads();
            #pragma unroll
            for (int j4 = eh * 4; j4 < eh * 4 + 4; ++j4) {
                const float4 t4 = *(const float4*)(Tf + o * 36 + 4 * j4);
                const float4 k4 = *(const float4*)(kwS + (o >> 7) * 128 + tau * 32 + 4 * j4);
                acc += t4.x * k4.x + t4.y * k4.y + t4.z * k4.z + t4.w * k4.w;
            }
        }
        red[eh][o] = acc;
        __syncthreads();
        if (tid < 256) wqkS[tid] = (red[0][tid] + red[1][tid]) * SCALE;
        __syncthreads();
    }

    // ---- D: score[hi][t] = x[t] . wqk[hi].  LDS-transpose tiles (x shared by both heads).
    {
        const int t = tid & 255, hi = tid >> 8;
        float acc = 0.f;
        for (int tau = 0; tau < 4; ++tau) {
            __syncthreads();
            #pragma unroll
            for (int r = 0; r < 4; ++r) {
                const int f4 = tid + 512 * r;
                const int tt = f4 >> 3, j4 = f4 & 7;
                const float4 v = *(const float4*)(xp0 + (size_t)tt * 128 + tau * 32 + 4 * j4);
                *(float4*)(Tf + tt * 36 + 4 * j4) = v;
            }
            __syncthreads();
            #pragma unroll
            for (int j4 = 0; j4 < 8; ++j4) {
                const float4 t4 = *(const float4*)(Tf + t * 36 + 4 * j4);
                const float4 q4 = *(const float4*)(wqkS + hi * 128 + tau * 32 + 4 * j4);
                acc += t4.x * q4.x + t4.y * q4.y + t4.z * q4.z + t4.w * q4.w;
            }
        }
        betaS[hi][t] = acc;
        __syncthreads();
    }

    // ---- softmax over t per head (thread = (hi, t))
    {
        const int t = tid & 255, hi = tid >> 8;
        const float v = betaS[hi][t];
        float m = v;
        #pragma unroll
        for (int off = 32; off; off >>= 1) m = fmaxf(m, __shfl_xor(m, off, 64));
        if (l == 0) smx[hi][w & 3] = m;
        __syncthreads();
        const float M = fmaxf(fmaxf(smx[hi][0], smx[hi][1]), fmaxf(smx[hi][2], smx[hi][3]));
        const float e = __expf(v - M);
        float ssum = e;
        #pragma unroll
        for (int off = 32; off; off >>= 1) ssum += __shfl_xor(ssum, off, 64);
        if (l == 0) sms[hi][w & 3] = ssum;
        __syncthreads();
        const float S = sms[hi][0] + sms[hi][1] + sms[hi][2] + sms[hi][3];
        betaS[hi][t] = e / S;
        __syncthreads();
    }

    // ---- E: xb[hi][d] = sum_t beta[hi][t]*x[t,d].  lane owns 4 d's, both heads.
    {
        const int q = tid & 31, tc = tid >> 5;
        float4 a0 = {0.f,0.f,0.f,0.f}, a1 = {0.f,0.f,0.f,0.f};
        const float4* xp = (const float4*)(xp0 + (size_t)(tc * 16) * 128 + 4 * q);
        #pragma unroll
        for (int j = 0; j < 16; ++j) {
            const float4 xv = xp[(size_t)j * 32];
            const float b0 = betaS[0][tc * 16 + j], b1 = betaS[1][tc * 16 + j];
            a0.x += b0 * xv.x; a0.y += b0 * xv.y; a0.z += b0 * xv.z; a0.w += b0 * xv.w;
            a1.x += b1 * xv.x; a1.y += b1 * xv.y; a1.z += b1 * xv.z; a1.w += b1 * xv.w;
        }
        *(float4*)(Tf + tc * 128 + 4 * q) = a0;
        *(float4*)(Tf + 2048 + tc * 128 + 4 * q) = a1;
        __syncthreads();
        if (tid < 256) {
            const int hi = tid >> 7, d = tid & 127;
            float v = 0.f;
            #pragma unroll
            for (int g = 0; g < 16; ++g) v += Tf[hi * 2048 + g * 128 + d];
            xbS[tid] = v;
        }
        __syncthreads();
    }

    // ---- F: res[he2] = xb[hi] . Wv[:,256p+he2] + bv.  lane owns 4 he2's.
    {
        const int q = tid & 63, kh = tid >> 6;
        const int hi = q >> 5;                      // he2=4q -> hi = q>>5
        float4 acc = {0.f, 0.f, 0.f, 0.f};
        const float4* wp = (const float4*)(Wv + (size_t)(kh * 16) * 1024 + 256 * p + 4 * q);
        #pragma unroll
        for (int j = 0; j < 16; ++j) {
            const float4 wv = wp[(size_t)j * 256];
            const float xv = xbS[hi * 128 + kh * 16 + j];
            acc.x += xv * wv.x; acc.y += xv * wv.y;
            acc.z += xv * wv.z; acc.w += xv * wv.w;
        }
        __syncthreads();                             // Tf free (E consumers done)
        *(float4*)(Tf + kh * 256 + 4 * q) = acc;
        __syncthreads();
        if (tid < 256) {
            float v = bv[256 * p + tid];
            #pragma unroll
            for (int g = 0; g < 8; ++g) v += Tf[g * 256 + tid];
            resS[tid] = v;
        }
        __syncthreads();
    }

    // ---- G: out-partial[d] over he in [256p, 256p+256).  lane owns 4 d's.
    {
        const int q = tid & 31, rh = tid >> 5;      // rh in [0,16)
        float4 acc = {0.f, 0.f, 0.f, 0.f};
        const float4* wp = (const float4*)(Wo + (size_t)(256 * p + rh * 16) * 128 + 4 * q);
        #pragma unroll
        for (int j = 0; j < 16; ++j) {
            const float4 wv = wp[(size_t)j * 32];
            const float rv = resS[rh * 16 + j];
            acc.x += rv * wv.x; acc.y += rv * wv.y;
            acc.z += rv * wv.z; acc.w += rv * wv.w;
        }
        *(float4*)(Tf + rh * 128 + 4 * q) = acc;
        __syncthreads();
    }

    // ---- cross-block reduce over p via d_ws (poisoned 0xAA != MAGIC each call)
    float* part = ws;                               // [64*4*128]
    unsigned* flags = (unsigned*)(ws + 32768);      // [256]
    if (p < 3) {
        if (tid < 128) {
            float v = 0.f;
            #pragma unroll
            for (int g = 0; g < 16; ++g) v += Tf[g * 128 + tid];
            part[(size_t)(b * 4 + p) * 128 + tid] = v;
            __threadfence();
        }
        __syncthreads();
        if (tid == 0) atomicExch(&flags[b * 4 + p], MAGIC);
    } else {
        if (tid == 0) {
            while (atomicCAS(&flags[b * 4 + 0], MAGIC, MAGIC) != MAGIC) {}
            while (atomicCAS(&flags[b * 4 + 1], MAGIC, MAGIC) != MAGIC) {}
            while (atomicCAS(&flags[b * 4 + 2], MAGIC, MAGIC) != MAGIC) {}
        }
        __syncthreads();
        if (tid < 128) {
            float v = bov[tid];
            #pragma unroll
            for (int g = 0; g < 16; ++g) v += Tf[g * 128 + tid];
            v += atomicAdd(&part[(size_t)(b * 4 + 0) * 128 + tid], 0.f);
            v += atomicAdd(&part[(size_t)(b * 4 + 1) * 128 + tid], 0.f);
            v += atomicAdd(&part[(size_t)(b * 4 + 2) * 128 + tid], 0.f);
            out[(size_t)b * 128 + tid] = v;
        }
    }
}

extern "C" void kernel_launch(void* const* d_in, const int* in_sizes, int n_in,
                              void* d_out, int out_size, void* d_ws, size_t ws_size,
                              hipStream_t stream) {
    const float* x  = (const float*)d_in[0];
    const float* Wq = (const float*)d_in[1];
    // d_in[2] = bq  — softmax shift-invariant, unused
    const float* Wk = (const float*)d_in[3];
    const float* bk = (const float*)d_in[4];
    const float* Wv = (const float*)d_in[5];
    const float* bv = (const float*)d_in[6];
    const float* Ws = (const float*)d_in[7];
    // d_in[8] = bs  — softmax shift-invariant, unused
    const float* Wo = (const float*)d_in[9];
    const float* bo = (const float*)d_in[10];
    float* out = (float*)d_out;
    float* ws  = (float*)d_ws;

    ta_one<<<dim3(64, 4), dim3(512), 0, stream>>>(x, Wq, Wk, bk, Wv, bv, Ws, Wo, bo, ws, out);
}

// Round 6
// 96.694 us; speedup vs baseline: 1.3307x; 1.0273x over previous
//
#include <hip/hip_runtime.h>
#include <hip/hip_bf16.h>

// B=64, T=256, D=128, H=8, E=128, H*E=1024.
// Algebra (verified R1-R5): with xw[b]=Ws^T x[b], Sw=sum(Ws):
//   Kw[b,he]   = xw[b] @ Wk[:,he] + Sw*bk[he]
//   wqk[b,h,d] = scale * sum_e Wq[d,h*128+e]*Kw[b,h,e]   (bq, bs drop: shift-invariant)
//   beta[b,h,t]= softmax_t( x[b,t] . wqk[b,h] )
//   xb[b,h,d]  = sum_t beta[b,h,t]*x[b,t,d]
//   res[b,he]  = xb[b,h] @ Wv[:,he] + bv[he]             (sum_t beta = 1)
//   out[b,d']  = res[b] @ Wo[:,d'] + bo[d']
//
// R6: one kernel, grid (64,4) x 512. Software-pipelined: each phase's 16xfloat4
// global loads are issued ONE PHASE EARLY into registers (the __syncthreads
// vmcnt(0) drain then overlaps a full phase of compute). C/D are register
// row-dots with interleaved chunk mapping (8 lanes cover 128B contiguous) and
// one padded LDS partial buffer (stride 257, conflict-free) — no transpose
// tiles, no per-tau barriers. Cross-block p-reduction: R5's flag handshake.

#define SCALE 0.08838834764831845f  // 1/sqrt(128)
#define MAGIC 0x13579BDFu

__global__ __launch_bounds__(512)
void ta_one(const float* __restrict__ x,  const float* __restrict__ Wq,
            const float* __restrict__ Wk, const float* __restrict__ bk,
            const float* __restrict__ Wv, const float* __restrict__ bv,
            const float* __restrict__ Wsv,
            const float* __restrict__ Wo, const float* __restrict__ bov,
            float* __restrict__ ws, float* __restrict__ out)
{
    __shared__ __align__(16) float pA[2056];      // partials (stride 257 for C/D)
    __shared__ __align__(16) float pB[2056];
    __shared__ __align__(16) float wsS[256];
    __shared__ __align__(16) float xwS[128];
    __shared__ __align__(16) float kwS[256];      // [hi][e]
    __shared__ __align__(16) float wqkS[256];     // [hi][d], pre-scaled
    __shared__ __align__(16) float betaS[2][256];
    __shared__ __align__(16) float xbS[256];      // [hi][d]
    __shared__ __align__(16) float resS[256];
    __shared__ float smx[2][4], sms[2][4];
    __shared__ float swS;

    const int tid = threadIdx.x;
    const int b = blockIdx.x, p = blockIdx.y;
    const int w = tid >> 6, l = tid & 63;
    const float* xp0 = x + (size_t)b * 32768;

    const int q5 = tid & 31, tc = tid >> 5;   // col-stream A/E/G: lane=4d, 16 chunks
    const int q6 = tid & 63, kh = tid >> 6;   // col-stream B/F: lane=4he, 8 chunks
    const int c8 = tid & 7,  r8 = tid >> 3;   // row-dot C/D: chunk c8, row-set r8

    // ---------- prefetch: A's x (cold) + B's Wk (cold) + small vectors ----------
    float4 rx[16];
    {
        const float4* xp = (const float4*)(xp0 + (size_t)(tc * 16) * 128 + 4 * q5);
        #pragma unroll
        for (int j = 0; j < 16; ++j) rx[j] = xp[(size_t)j * 32];
    }
    float4 rwk[16];
    {
        const float4* wp = (const float4*)(Wk + (size_t)(kh * 16) * 1024 + 256 * p + 4 * q6);
        #pragma unroll
        for (int j = 0; j < 16; ++j) rwk[j] = wp[(size_t)j * 256];
    }
    const float bkv = bk[256 * p + (tid & 255)];
    const float bvv = bv[256 * p + (tid & 255)];
    if (tid < 64) *(float4*)(wsS + 4 * tid) = *(const float4*)(Wsv + 4 * tid);
    __syncthreads();

    // ---------- A: xw partials ----------
    {
        float4 acc = {0.f, 0.f, 0.f, 0.f};
        #pragma unroll
        for (int j = 0; j < 16; ++j) {
            const float s = wsS[tc * 16 + j];
            acc.x += s * rx[j].x; acc.y += s * rx[j].y;
            acc.z += s * rx[j].z; acc.w += s * rx[j].w;
        }
        *(float4*)(pA + tc * 128 + 4 * q5) = acc;
    }
    // prefetch C's Wq row-chunks (cold) — interleaved mapping: 8 lanes = 128B
    float4 rwq[16];
    {
        #pragma unroll
        for (int rr = 0; rr < 4; ++rr) {
            const int o = r8 + 64 * rr;            // o = hi*128+d
            const float* base = Wq + (size_t)(o & 127) * 1024 + (2 * p + (o >> 7)) * 128;
            #pragma unroll
            for (int jj = 0; jj < 4; ++jj)
                rwq[rr * 4 + jj] = *(const float4*)(base + (jj * 8 + c8) * 4);
        }
    }
    __syncthreads();
    if (tid < 128) {
        float v = 0.f;
        #pragma unroll
        for (int g = 0; g < 16; ++g) v += pA[g * 128 + tid];
        xwS[tid] = v;
    } else if (tid < 192) {                        // Sw
        float v = wsS[l] + wsS[l + 64] + wsS[l + 128] + wsS[l + 192];
        #pragma unroll
        for (int off = 32; off; off >>= 1) v += __shfl_xor(v, off, 64);
        if (l == 0) swS = v;
    }
    __syncthreads();

    // ---------- B: Kw partials ----------
    {
        float4 acc = {0.f, 0.f, 0.f, 0.f};
        #pragma unroll
        for (int j = 0; j < 16; ++j) {
            const float xv = xwS[kh * 16 + j];
            acc.x += xv * rwk[j].x; acc.y += xv * rwk[j].y;
            acc.z += xv * rwk[j].z; acc.w += xv * rwk[j].w;
        }
        *(float4*)(pB + kh * 256 + 4 * q6) = acc;
    }
    // prefetch D's x rows (L2-hot) — same interleaved mapping
    float4 rxd[16];
    {
        #pragma unroll
        for (int rr = 0; rr < 4; ++rr) {
            const int t = r8 + 64 * rr;
            const float* base = xp0 + (size_t)t * 128;
            #pragma unroll
            for (int jj = 0; jj < 4; ++jj)
                rxd[rr * 4 + jj] = *(const float4*)(base + (jj * 8 + c8) * 4);
        }
    }
    __syncthreads();
    if (tid < 256) {
        float v = swS * bkv;
        #pragma unroll
        for (int g = 0; g < 8; ++g) v += pB[g * 256 + tid];
        kwS[tid] = v;
    }
    __syncthreads();

    // ---------- C: wqk row-dots ----------
    {
        #pragma unroll
        for (int rr = 0; rr < 4; ++rr) {
            const int o = r8 + 64 * rr;
            const float* kp = kwS + (o >> 7) * 128;
            float a = 0.f;
            #pragma unroll
            for (int jj = 0; jj < 4; ++jj) {
                const float4 wv = rwq[rr * 4 + jj];
                const float* kk = kp + (jj * 8 + c8) * 4;
                a += wv.x * kk[0] + wv.y * kk[1] + wv.z * kk[2] + wv.w * kk[3];
            }
            pA[c8 * 257 + o] = a;
        }
    }
    // prefetch F's Wv (cold)
    float4 rwv[16];
    {
        const float4* wp = (const float4*)(Wv + (size_t)(kh * 16) * 1024 + 256 * p + 4 * q6);
        #pragma unroll
        for (int j = 0; j < 16; ++j) rwv[j] = wp[(size_t)j * 256];
    }
    __syncthreads();
    if (tid < 256) {
        float v = 0.f;
        #pragma unroll
        for (int g = 0; g < 8; ++g) v += pA[g * 257 + tid];
        wqkS[tid] = v * SCALE;
    }
    __syncthreads();

    // ---------- D: score row-dots (both heads) ----------
    {
        #pragma unroll
        for (int rr = 0; rr < 4; ++rr) {
            const int t = r8 + 64 * rr;
            float a0 = 0.f, a1 = 0.f;
            #pragma unroll
            for (int jj = 0; jj < 4; ++jj) {
                const float4 xv = rxd[rr * 4 + jj];
                const float* q0 = wqkS + (jj * 8 + c8) * 4;
                const float* q1 = wqkS + 128 + (jj * 8 + c8) * 4;
                a0 += xv.x * q0[0] + xv.y * q0[1] + xv.z * q0[2] + xv.w * q0[3];
                a1 += xv.x * q1[0] + xv.y * q1[1] + xv.z * q1[2] + xv.w * q1[3];
            }
            pA[c8 * 257 + t] = a0;
            pB[c8 * 257 + t] = a1;
        }
    }
    // prefetch E's x (L2-hot, same addresses as A)
    float4 rxe[16];
    {
        const float4* xp = (const float4*)(xp0 + (size_t)(tc * 16) * 128 + 4 * q5);
        #pragma unroll
        for (int j = 0; j < 16; ++j) rxe[j] = xp[(size_t)j * 32];
    }
    __syncthreads();

    // ---------- softmax over t per head (thread = (hi, t)) ----------
    {
        const int t = tid & 255, hi = tid >> 8;
        const float* pS = hi ? pB : pA;
        float v = 0.f;
        #pragma unroll
        for (int g = 0; g < 8; ++g) v += pS[g * 257 + t];
        float m = v;
        #pragma unroll
        for (int off = 32; off; off >>= 1) m = fmaxf(m, __shfl_xor(m, off, 64));
        if (l == 0) smx[hi][w & 3] = m;
        __syncthreads();
        const float M = fmaxf(fmaxf(smx[hi][0], smx[hi][1]), fmaxf(smx[hi][2], smx[hi][3]));
        const float e = __expf(v - M);
        float ssum = e;
        #pragma unroll
        for (int off = 32; off; off >>= 1) ssum += __shfl_xor(ssum, off, 64);
        if (l == 0) sms[hi][w & 3] = ssum;
        __syncthreads();
        const float S = sms[hi][0] + sms[hi][1] + sms[hi][2] + sms[hi][3];
        betaS[hi][t] = e / S;
        __syncthreads();
    }

    // ---------- E: xb partials (both heads) ----------
    {
        float4 a0 = {0.f,0.f,0.f,0.f}, a1 = {0.f,0.f,0.f,0.f};
        #pragma unroll
        for (int j = 0; j < 16; ++j) {
            const float b0 = betaS[0][tc * 16 + j], b1 = betaS[1][tc * 16 + j];
            a0.x += b0 * rxe[j].x; a0.y += b0 * rxe[j].y;
            a0.z += b0 * rxe[j].z; a0.w += b0 * rxe[j].w;
            a1.x += b1 * rxe[j].x; a1.y += b1 * rxe[j].y;
            a1.z += b1 * rxe[j].z; a1.w += b1 * rxe[j].w;
        }
        *(float4*)(pA + tc * 128 + 4 * q5) = a0;
        *(float4*)(pB + tc * 128 + 4 * q5) = a1;
    }
    __syncthreads();
    if (tid < 256) {
        const int hi = tid >> 7, d = tid & 127;
        const float* pp = hi ? pB : pA;
        float v = 0.f;
        #pragma unroll
        for (int g = 0; g < 16; ++g) v += pp[g * 128 + d];
        xbS[tid] = v;
    }
    __syncthreads();

    // ---------- F: res partials ----------
    {
        const int hi = q6 >> 5;
        float4 acc = {0.f, 0.f, 0.f, 0.f};
        #pragma unroll
        for (int j = 0; j < 16; ++j) {
            const float xv = xbS[hi * 128 + kh * 16 + j];
            acc.x += xv * rwv[j].x; acc.y += xv * rwv[j].y;
            acc.z += xv * rwv[j].z; acc.w += xv * rwv[j].w;
        }
        *(float4*)(pB + kh * 256 + 4 * q6) = acc;
    }
    // prefetch G's Wo (cold)
    float4 rwo[16];
    {
        const float4* wp = (const float4*)(Wo + (size_t)(256 * p + tc * 16) * 128 + 4 * q5);
        #pragma unroll
        for (int j = 0; j < 16; ++j) rwo[j] = wp[(size_t)j * 32];
    }
    __syncthreads();
    if (tid < 256) {
        float v = bvv;
        #pragma unroll
        for (int g = 0; g < 8; ++g) v += pB[g * 256 + tid];
        resS[tid] = v;
    }
    __syncthreads();

    // ---------- G: out-partials over this he-chunk ----------
    {
        float4 acc = {0.f, 0.f, 0.f, 0.f};
        #pragma unroll
        for (int j = 0; j < 16; ++j) {
            const float rv = resS[tc * 16 + j];
            acc.x += rv * rwo[j].x; acc.y += rv * rwo[j].y;
            acc.z += rv * rwo[j].z; acc.w += rv * rwo[j].w;
        }
        *(float4*)(pA + tc * 128 + 4 * q5) = acc;
    }
    __syncthreads();

    // ---------- cross-block reduce over p (R5 handshake; ws poisoned 0xAA) ----
    float* part = ws;                               // [64*4*128]
    unsigned* flags = (unsigned*)(ws + 32768);      // [256]
    if (p < 3) {
        if (tid < 128) {
            float v = 0.f;
            #pragma unroll
            for (int g = 0; g < 16; ++g) v += pA[g * 128 + tid];
            part[(size_t)(b * 4 + p) * 128 + tid] = v;
            __threadfence();
        }
        __syncthreads();
        if (tid == 0) atomicExch(&flags[b * 4 + p], MAGIC);
    } else {
        if (tid == 0) {
            while (atomicCAS(&flags[b * 4 + 0], MAGIC, MAGIC) != MAGIC) {}
            while (atomicCAS(&flags[b * 4 + 1], MAGIC, MAGIC) != MAGIC) {}
            while (atomicCAS(&flags[b * 4 + 2], MAGIC, MAGIC) != MAGIC) {}
        }
        __syncthreads();
        if (tid < 128) {
            float v = bov[tid];
            #pragma unroll
            for (int g = 0; g < 16; ++g) v += pA[g * 128 + tid];
            v += atomicAdd(&part[(size_t)(b * 4 + 0) * 128 + tid], 0.f);
            v += atomicAdd(&part[(size_t)(b * 4 + 1) * 128 + tid], 0.f);
            v += atomicAdd(&part[(size_t)(b * 4 + 2) * 128 + tid], 0.f);
            out[(size_t)b * 128 + tid] = v;
        }
    }
}

extern "C" void kernel_launch(void* const* d_in, const int* in_sizes, int n_in,
                              void* d_out, int out_size, void* d_ws, size_t ws_size,
                              hipStream_t stream) {
    const float* x  = (const float*)d_in[0];
    const float* Wq = (const float*)d_in[1];
    // d_in[2] = bq  — softmax shift-invariant, unused
    const float* Wk = (const float*)d_in[3];
    const float* bk = (const float*)d_in[4];
    const float* Wv = (const float*)d_in[5];
    const float* bv = (const float*)d_in[6];
    const float* Ws = (const float*)d_in[7];
    // d_in[8] = bs  — softmax shift-invariant, unused
    const float* Wo = (const float*)d_in[9];
    const float* bo = (const float*)d_in[10];
    float* out = (float*)d_out;
    float* ws  = (float*)d_ws;

    ta_one<<<dim3(64, 4), dim3(512), 0, stream>>>(x, Wq, Wk, bk, Wv, bv, Ws, Wo, bo, ws, out);
}

// Round 7
// 94.572 us; speedup vs baseline: 1.3605x; 1.0224x over previous
//
#include <hip/hip_runtime.h>
#include <hip/hip_bf16.h>

// B=64, T=256, D=128, H=8, E=128, H*E=1024.
// Algebra (verified R1-R6): with xw[b]=Ws^T x[b], Sw=sum(Ws):
//   Kw[b,he]   = xw[b] @ Wk[:,he] + Sw*bk[he]
//   wqk[b,h,d] = scale * sum_e Wq[d,h*128+e]*Kw[b,h,e]   (bq, bs drop: shift-invariant)
//   beta[b,h,t]= softmax_t( x[b,t] . wqk[b,h] )
//   xb[b,h,d]  = sum_t beta[b,h,t]*x[b,t,d]
//   res[b,he]  = xb[b,h] @ Wv[:,he] + bv[he]             (sum_t beta = 1)
//   out[b,d']  = res[b] @ Wo[:,d'] + bo[d']
//
// R7: R6 skeleton + TWO fixes:
//  (1) inter-phase barriers are `s_waitcnt lgkmcnt(0); s_barrier` (volatile asm)
//      — LDS partials are ordered, but global prefetch loads STAY IN FLIGHT
//      across the barrier (the __syncthreads vmcnt(0) drain was nullifying all
//      of R6's phase-early prefetching — guide §5/m97: compiler emits full
//      vmcnt(0) before s_barrier).
//  (2) strict 2-live prefetch arrays (Wv load moved C->E) — caps VGPR ~170,
//      no scratch spill.

#define SCALE 0.08838834764831845f  // 1/sqrt(128)
#define MAGIC 0x13579BDFu

// LDS-ordering barrier that does NOT drain vmcnt (global loads stay in flight).
#define BAR() __asm__ volatile("s_waitcnt lgkmcnt(0)\n\ts_barrier" ::: "memory")

__global__ __launch_bounds__(512)
void ta_one(const float* __restrict__ x,  const float* __restrict__ Wq,
            const float* __restrict__ Wk, const float* __restrict__ bk,
            const float* __restrict__ Wv, const float* __restrict__ bv,
            const float* __restrict__ Wsv,
            const float* __restrict__ Wo, const float* __restrict__ bov,
            float* __restrict__ ws, float* __restrict__ out)
{
    __shared__ __align__(16) float pA[2056];      // partials (stride 257 for C/D)
    __shared__ __align__(16) float pB[2056];
    __shared__ __align__(16) float wsS[256];
    __shared__ __align__(16) float xwS[128];
    __shared__ __align__(16) float kwS[256];      // [hi][e]
    __shared__ __align__(16) float wqkS[256];     // [hi][d], pre-scaled
    __shared__ __align__(16) float betaS[2][256];
    __shared__ __align__(16) float xbS[256];      // [hi][d]
    __shared__ __align__(16) float resS[256];
    __shared__ float smx[2][4], sms[2][4];
    __shared__ float swS;

    const int tid = threadIdx.x;
    const int b = blockIdx.x, p = blockIdx.y;
    const int w = tid >> 6, l = tid & 63;
    const float* xp0 = x + (size_t)b * 32768;

    const int q5 = tid & 31, tc = tid >> 5;   // col-stream A/E/G: lane=4d, 16 chunks
    const int q6 = tid & 63, kh = tid >> 6;   // col-stream B/F: lane=4he, 8 chunks
    const int c8 = tid & 7,  r8 = tid >> 3;   // row-dot C/D: chunk c8, row-set r8

    // ---------- prefetch: A's x (cold) + B's Wk (cold) + small vectors ----------
    float4 rx[16];
    {
        const float4* xp = (const float4*)(xp0 + (size_t)(tc * 16) * 128 + 4 * q5);
        #pragma unroll
        for (int j = 0; j < 16; ++j) rx[j] = xp[(size_t)j * 32];
    }
    float4 rwk[16];
    {
        const float4* wp = (const float4*)(Wk + (size_t)(kh * 16) * 1024 + 256 * p + 4 * q6);
        #pragma unroll
        for (int j = 0; j < 16; ++j) rwk[j] = wp[(size_t)j * 256];
    }
    const float bkv = bk[256 * p + (tid & 255)];
    const float bvv = bv[256 * p + (tid & 255)];
    if (tid < 64) *(float4*)(wsS + 4 * tid) = *(const float4*)(Wsv + 4 * tid);
    BAR();

    // ---------- A: xw partials (uses rx; rx dies here) ----------
    {
        float4 acc = {0.f, 0.f, 0.f, 0.f};
        #pragma unroll
        for (int j = 0; j < 16; ++j) {
            const float s = wsS[tc * 16 + j];
            acc.x += s * rx[j].x; acc.y += s * rx[j].y;
            acc.z += s * rx[j].z; acc.w += s * rx[j].w;
        }
        *(float4*)(pA + tc * 128 + 4 * q5) = acc;
    }
    // prefetch C's Wq row-chunks (cold) — interleaved mapping: 8 lanes = 128B
    float4 rwq[16];
    {
        #pragma unroll
        for (int rr = 0; rr < 4; ++rr) {
            const int o = r8 + 64 * rr;            // o = hi*128+d
            const float* base = Wq + (size_t)(o & 127) * 1024 + (2 * p + (o >> 7)) * 128;
            #pragma unroll
            for (int jj = 0; jj < 4; ++jj)
                rwq[rr * 4 + jj] = *(const float4*)(base + (jj * 8 + c8) * 4);
        }
    }
    BAR();
    if (tid < 128) {
        float v = 0.f;
        #pragma unroll
        for (int g = 0; g < 16; ++g) v += pA[g * 128 + tid];
        xwS[tid] = v;
    } else if (tid < 192) {                        // Sw
        float v = wsS[l] + wsS[l + 64] + wsS[l + 128] + wsS[l + 192];
        #pragma unroll
        for (int off = 32; off; off >>= 1) v += __shfl_xor(v, off, 64);
        if (l == 0) swS = v;
    }
    BAR();

    // ---------- B: Kw partials (uses rwk; dies) ----------
    {
        float4 acc = {0.f, 0.f, 0.f, 0.f};
        #pragma unroll
        for (int j = 0; j < 16; ++j) {
            const float xv = xwS[kh * 16 + j];
            acc.x += xv * rwk[j].x; acc.y += xv * rwk[j].y;
            acc.z += xv * rwk[j].z; acc.w += xv * rwk[j].w;
        }
        *(float4*)(pB + kh * 256 + 4 * q6) = acc;
    }
    // prefetch D's x rows — interleaved mapping (in flight through C)
    float4 rxd[16];
    {
        #pragma unroll
        for (int rr = 0; rr < 4; ++rr) {
            const int t = r8 + 64 * rr;
            const float* base = xp0 + (size_t)t * 128;
            #pragma unroll
            for (int jj = 0; jj < 4; ++jj)
                rxd[rr * 4 + jj] = *(const float4*)(base + (jj * 8 + c8) * 4);
        }
    }
    BAR();
    if (tid < 256) {
        float v = swS * bkv;
        #pragma unroll
        for (int g = 0; g < 8; ++g) v += pB[g * 256 + tid];
        kwS[tid] = v;
    }
    BAR();

    // ---------- C: wqk row-dots (uses rwq; dies) ----------
    {
        #pragma unroll
        for (int rr = 0; rr < 4; ++rr) {
            const int o = r8 + 64 * rr;
            const float* kp = kwS + (o >> 7) * 128;
            float a = 0.f;
            #pragma unroll
            for (int jj = 0; jj < 4; ++jj) {
                const float4 wv = rwq[rr * 4 + jj];
                const float* kk = kp + (jj * 8 + c8) * 4;
                a += wv.x * kk[0] + wv.y * kk[1] + wv.z * kk[2] + wv.w * kk[3];
            }
            pA[c8 * 257 + o] = a;
        }
    }
    BAR();
    if (tid < 256) {
        float v = 0.f;
        #pragma unroll
        for (int g = 0; g < 8; ++g) v += pA[g * 257 + tid];
        wqkS[tid] = v * SCALE;
    }
    BAR();

    // ---------- D: score row-dots (uses rxd; dies) ----------
    {
        #pragma unroll
        for (int rr = 0; rr < 4; ++rr) {
            const int t = r8 + 64 * rr;
            float a0 = 0.f, a1 = 0.f;
            #pragma unroll
            for (int jj = 0; jj < 4; ++jj) {
                const float4 xv = rxd[rr * 4 + jj];
                const float* q0 = wqkS + (jj * 8 + c8) * 4;
                const float* q1 = wqkS + 128 + (jj * 8 + c8) * 4;
                a0 += xv.x * q0[0] + xv.y * q0[1] + xv.z * q0[2] + xv.w * q0[3];
                a1 += xv.x * q1[0] + xv.y * q1[1] + xv.z * q1[2] + xv.w * q1[3];
            }
            pA[c8 * 257 + t] = a0;
            pB[c8 * 257 + t] = a1;
        }
    }
    // prefetch E's x (L2-hot; in flight through softmax)
    float4 rxe[16];
    {
        const float4* xp = (const float4*)(xp0 + (size_t)(tc * 16) * 128 + 4 * q5);
        #pragma unroll
        for (int j = 0; j < 16; ++j) rxe[j] = xp[(size_t)j * 32];
    }
    BAR();

    // ---------- softmax over t per head (thread = (hi, t)) ----------
    {
        const int t = tid & 255, hi = tid >> 8;
        const float* pS = hi ? pB : pA;
        float v = 0.f;
        #pragma unroll
        for (int g = 0; g < 8; ++g) v += pS[g * 257 + t];
        float m = v;
        #pragma unroll
        for (int off = 32; off; off >>= 1) m = fmaxf(m, __shfl_xor(m, off, 64));
        if (l == 0) smx[hi][w & 3] = m;
        BAR();
        const float M = fmaxf(fmaxf(smx[hi][0], smx[hi][1]), fmaxf(smx[hi][2], smx[hi][3]));
        const float e = __expf(v - M);
        float ssum = e;
        #pragma unroll
        for (int off = 32; off; off >>= 1) ssum += __shfl_xor(ssum, off, 64);
        if (l == 0) sms[hi][w & 3] = ssum;
        BAR();
        const float S = sms[hi][0] + sms[hi][1] + sms[hi][2] + sms[hi][3];
        betaS[hi][t] = e / S;
    }
    BAR();

    // ---------- E: xb partials (uses rxe; dies) ----------
    {
        float4 a0 = {0.f,0.f,0.f,0.f}, a1 = {0.f,0.f,0.f,0.f};
        #pragma unroll
        for (int j = 0; j < 16; ++j) {
            const float b0 = betaS[0][tc * 16 + j], b1 = betaS[1][tc * 16 + j];
            a0.x += b0 * rxe[j].x; a0.y += b0 * rxe[j].y;
            a0.z += b0 * rxe[j].z; a0.w += b0 * rxe[j].w;
            a1.x += b1 * rxe[j].x; a1.y += b1 * rxe[j].y;
            a1.z += b1 * rxe[j].z; a1.w += b1 * rxe[j].w;
        }
        *(float4*)(pA + tc * 128 + 4 * q5) = a0;
        *(float4*)(pB + tc * 128 + 4 * q5) = a1;
    }
    // prefetch F's Wv (cold) — moved here from C (2-live-array discipline)
    float4 rwv[16];
    {
        const float4* wp = (const float4*)(Wv + (size_t)(kh * 16) * 1024 + 256 * p + 4 * q6);
        #pragma unroll
        for (int j = 0; j < 16; ++j) rwv[j] = wp[(size_t)j * 256];
    }
    BAR();
    if (tid < 256) {
        const int hi = tid >> 7, d = tid & 127;
        const float* pp = hi ? pB : pA;
        float v = 0.f;
        #pragma unroll
        for (int g = 0; g < 16; ++g) v += pp[g * 128 + d];
        xbS[tid] = v;
    }
    BAR();

    // ---------- F: res partials (uses rwv; dies) ----------
    {
        const int hi = q6 >> 5;
        float4 acc = {0.f, 0.f, 0.f, 0.f};
        #pragma unroll
        for (int j = 0; j < 16; ++j) {
            const float xv = xbS[hi * 128 + kh * 16 + j];
            acc.x += xv * rwv[j].x; acc.y += xv * rwv[j].y;
            acc.z += xv * rwv[j].z; acc.w += xv * rwv[j].w;
        }
        *(float4*)(pB + kh * 256 + 4 * q6) = acc;
    }
    // prefetch G's Wo (cold)
    float4 rwo[16];
    {
        const float4* wp = (const float4*)(Wo + (size_t)(256 * p + tc * 16) * 128 + 4 * q5);
        #pragma unroll
        for (int j = 0; j < 16; ++j) rwo[j] = wp[(size_t)j * 32];
    }
    BAR();
    if (tid < 256) {
        float v = bvv;
        #pragma unroll
        for (int g = 0; g < 8; ++g) v += pB[g * 256 + tid];
        resS[tid] = v;
    }
    BAR();

    // ---------- G: out-partials (uses rwo; dies) ----------
    {
        float4 acc = {0.f, 0.f, 0.f, 0.f};
        #pragma unroll
        for (int j = 0; j < 16; ++j) {
            const float rv = resS[tc * 16 + j];
            acc.x += rv * rwo[j].x; acc.y += rv * rwo[j].y;
            acc.z += rv * rwo[j].z; acc.w += rv * rwo[j].w;
        }
        *(float4*)(pA + tc * 128 + 4 * q5) = acc;
    }
    __syncthreads();   // full barrier before handshake (global-store ordering next)

    // ---------- cross-block reduce over p (ws poisoned 0xAA each call) ----------
    float* part = ws;                               // [64*4*128]
    unsigned* flags = (unsigned*)(ws + 32768);      // [256]
    if (p < 3) {
        if (tid < 128) {
            float v = 0.f;
            #pragma unroll
            for (int g = 0; g < 16; ++g) v += pA[g * 128 + tid];
            part[(size_t)(b * 4 + p) * 128 + tid] = v;
            __threadfence();
        }
        __syncthreads();
        if (tid == 0) atomicExch(&flags[b * 4 + p], MAGIC);
    } else {
        if (tid == 0) {
            while (atomicCAS(&flags[b * 4 + 0], MAGIC, MAGIC) != MAGIC) {}
            while (atomicCAS(&flags[b * 4 + 1], MAGIC, MAGIC) != MAGIC) {}
            while (atomicCAS(&flags[b * 4 + 2], MAGIC, MAGIC) != MAGIC) {}
        }
        __syncthreads();
        if (tid < 128) {
            float v = bov[tid];
            #pragma unroll
            for (int g = 0; g < 16; ++g) v += pA[g * 128 + tid];
            v += atomicAdd(&part[(size_t)(b * 4 + 0) * 128 + tid], 0.f);
            v += atomicAdd(&part[(size_t)(b * 4 + 1) * 128 + tid], 0.f);
            v += atomicAdd(&part[(size_t)(b * 4 + 2) * 128 + tid], 0.f);
            out[(size_t)b * 128 + tid] = v;
        }
    }
}

extern "C" void kernel_launch(void* const* d_in, const int* in_sizes, int n_in,
                              void* d_out, int out_size, void* d_ws, size_t ws_size,
                              hipStream_t stream) {
    const float* x  = (const float*)d_in[0];
    const float* Wq = (const float*)d_in[1];
    // d_in[2] = bq  — softmax shift-invariant, unused
    const float* Wk = (const float*)d_in[3];
    const float* bk = (const float*)d_in[4];
    const float* Wv = (const float*)d_in[5];
    const float* bv = (const float*)d_in[6];
    const float* Ws = (const float*)d_in[7];
    // d_in[8] = bs  — softmax shift-invariant, unused
    const float* Wo = (const float*)d_in[9];
    const float* bo = (const float*)d_in[10];
    float* out = (float*)d_out;
    float* ws  = (float*)d_ws;

    ta_one<<<dim3(64, 4), dim3(512), 0, stream>>>(x, Wq, Wk, bk, Wv, bv, Ws, Wo, bo, ws, out);
}